// Round 6
// baseline (59.279 us; speedup 1.0000x reference)
//
#include <hip/hip_runtime.h>
#include <cmath>

// NCE LM loss. N = B*T rows, D = 1024, K = 20 noise ids, V = vocab.
// R6: R5's lean per-block work (one row/block, 2048 blocks x 256 thr,
// register hidden chunk, batched butterflies, lane-parallel log-sigmoid,
// normalization folded into per-block contribution) + fused last-block
// finalize (counter zeroed by a 4B memset node each call).

#define KN 20            // noise count (fast path)

__device__ __forceinline__ float log_sigmoid_f(float x) {
    // stable log(sigmoid(x)) = min(x,0) - log1p(exp(-|x|))
    return fminf(x, 0.0f) - log1pf(expf(-fabsf(x)));
}

__device__ __forceinline__ float fma4(float4 a, float4 b, float acc) {
    acc = fmaf(a.x, b.x, acc);
    acc = fmaf(a.y, b.y, acc);
    acc = fmaf(a.z, b.z, acc);
    return fmaf(a.w, b.w, acc);
}

__device__ __forceinline__ float wave_reduce(float v) {
    #pragma unroll
    for (int off = 32; off > 0; off >>= 1) v += __shfl_xor(v, off, 64);
    return v;
}

// One row per block. Wave w owns ids {w, w+4, ...} <= 20 (id 0 = target row).
__global__ __launch_bounds__(256) void nce_fused_kernel(
    const float* __restrict__ hidden,     // (N, 1024)
    const int*   __restrict__ targets,    // (N,)
    const float* __restrict__ W,          // (V, 1024)
    const int*   __restrict__ noise_ids,  // (20,)
    float* __restrict__ cb,               // (N,) per-block loss contributions
    int*   __restrict__ counter,          // zeroed by memset node each call
    float* __restrict__ out,
    float inv_n, float inv_nk, float shift)
{
    __shared__ float sc4[4];
    __shared__ int   slast;

    const int row  = blockIdx.x;
    const int tid  = threadIdx.x;
    const int wave = tid >> 6;
    const int lane = tid & 63;
    const int nblocks = gridDim.x;

    // Hidden row chunk in registers: lane owns elems {lane*4 + j*256}.
    const float* hrow = hidden + (size_t)row * 1024;
    float4 h[4];
    #pragma unroll
    for (int j = 0; j < 4; ++j)
        h[j] = *reinterpret_cast<const float4*>(hrow + lane * 4 + j * 256);

    const int tgt = targets[row];

    // Phase 1: lane-local partials for up to 6 dots (static accumulators).
    float acc[6];
    #pragma unroll
    for (int s = 0; s < 6; ++s) {
        const int id = wave + 4 * s;
        float a = 0.0f;
        if (id <= KN) {
            const int wrow = (id == 0) ? tgt : noise_ids[id - 1];
            const float* wr = W + (size_t)wrow * 1024;
            #pragma unroll
            for (int j = 0; j < 4; ++j) {
                const float4 b = *reinterpret_cast<const float4*>(wr + lane * 4 + j * 256);
                a = fma4(h[j], b, a);
            }
        }
        acc[s] = a;
    }

    // Phase 2: 6 butterflies, round-major so independent chains pipeline.
    #pragma unroll
    for (int off = 32; off > 0; off >>= 1)
        #pragma unroll
        for (int s = 0; s < 6; ++s)
            acc[s] += __shfl_xor(acc[s], off, 64);

    // Phase 3: lanes 0..5 evaluate their log-sigmoid term in parallel.
    float v = acc[0];
    v = (lane == 1) ? acc[1] : v;
    v = (lane == 2) ? acc[2] : v;
    v = (lane == 3) ? acc[3] : v;
    v = (lane == 4) ? acc[4] : v;
    v = (lane == 5) ? acc[5] : v;
    const int id = wave + 4 * lane;
    float term = 0.0f;
    if (lane < 6 && id <= KN) {
        const float sc = v + shift;
        term = (id == 0) ? (-log_sigmoid_f(sc)) * inv_n
                         : (-log_sigmoid_f(-sc)) * inv_nk;
    }
    term += __shfl_xor(term, 1, 64);
    term += __shfl_xor(term, 2, 64);
    term += __shfl_xor(term, 4, 64);

    if (lane == 0) sc4[wave] = term;
    __syncthreads();
    if (tid == 0) {
        cb[row] = sc4[0] + sc4[1] + sc4[2] + sc4[3];
        // release side of the fetch_add publishes cb[row] device-wide
        slast = (__hip_atomic_fetch_add(counter, 1, __ATOMIC_ACQ_REL,
                                        __HIP_MEMORY_SCOPE_AGENT) == nblocks - 1);
    }
    __syncthreads();
    if (!slast) return;

    // ---- last arriving block: deterministic fixed-tree sum of cb[0..N) ----
    float p = 0.0f;
    for (int i = tid; i < nblocks; i += 256)
        p += __hip_atomic_load(&cb[i], __ATOMIC_ACQUIRE, __HIP_MEMORY_SCOPE_AGENT);
    p = wave_reduce(p);
    if (lane == 0) sc4[wave] = p;
    __syncthreads();
    if (tid == 0) out[0] = sc4[0] + sc4[1] + sc4[2] + sc4[3];
}

// ---- generic fallback for unexpected shapes: one block per row + sum ----
__global__ __launch_bounds__(256) void nce_generic_kernel(
    const float* __restrict__ hidden, const int* __restrict__ targets,
    const float* __restrict__ W, const int* __restrict__ noise_ids,
    float* __restrict__ cb, int D, int K, float inv_n, float inv_nk, float shift)
{
    const int row  = blockIdx.x;
    const int tid  = threadIdx.x;
    const int wave = tid >> 6;
    const int lane = tid & 63;
    __shared__ float sc4[4];

    const float* hrow = hidden + (size_t)row * D;
    const int tgt = targets[row];
    float c = 0.0f;
    for (int id = wave; id <= K; id += 4) {
        const int wrow = (id == 0) ? tgt : noise_ids[id - 1];
        const float* wv = W + (size_t)wrow * D;
        float acc = 0.0f;
        for (int k = lane; k < D; k += 64) acc = fmaf(hrow[k], wv[k], acc);
        acc = wave_reduce(acc);
        if (lane == 0) {
            const float s = acc + shift;
            c += (id == 0) ? (-log_sigmoid_f(s)) * inv_n
                           : (-log_sigmoid_f(-s)) * inv_nk;
        }
    }
    if (lane == 0) sc4[wave] = c;
    __syncthreads();
    if (tid == 0) cb[row] = sc4[0] + sc4[1] + sc4[2] + sc4[3];
}

__global__ __launch_bounds__(256) void nce_sum_kernel(
    const float* __restrict__ cb, float* __restrict__ out, int n)
{
    __shared__ float sp[4];
    const int tid  = threadIdx.x;
    const int wave = tid >> 6;
    const int lane = tid & 63;

    float p = 0.0f;
    for (int i = tid; i < n; i += 256) p += cb[i];
    p = wave_reduce(p);
    if (lane == 0) sp[wave] = p;
    __syncthreads();
    if (tid == 0) out[0] = sp[0] + sp[1] + sp[2] + sp[3];
}

extern "C" void kernel_launch(void* const* d_in, const int* in_sizes, int n_in,
                              void* d_out, int out_size, void* d_ws, size_t ws_size,
                              hipStream_t stream) {
    const float* hidden    = (const float*)d_in[0];
    const int*   targets   = (const int*)d_in[1];
    const float* W         = (const float*)d_in[2];
    const int*   noise_ids = (const int*)d_in[3];

    const int N = in_sizes[1];             // B*T = 2048
    const int D = in_sizes[0] / N;         // 1024
    const int K = in_sizes[3];             // 20
    const int V = in_sizes[2] / D;         // 50257

    const float shift  = logf((float)V) - logf((float)K);
    const float inv_n  = 1.0f / (float)N;
    const float inv_nk = 1.0f / ((float)N * (float)K);

    float* cb = (float*)d_ws;              // N floats, all overwritten each call
    int* counter = (int*)(cb + N);         // 4 bytes, re-zeroed every call

    if (D == 1024 && K == KN) {
        hipMemsetAsync(counter, 0, sizeof(int), stream);
        nce_fused_kernel<<<N, 256, 0, stream>>>(
            hidden, targets, W, noise_ids, cb, counter, (float*)d_out,
            inv_n, inv_nk, shift);
    } else {
        nce_generic_kernel<<<N, 256, 0, stream>>>(
            hidden, targets, W, noise_ids, cb, D, K, inv_n, inv_nk, shift);
        nce_sum_kernel<<<1, 256, 0, stream>>>(cb, (float*)d_out, N);
    }
}

// Round 7
// 17.813 us; speedup vs baseline: 3.3278x; 3.3278x over previous
//
#include <hip/hip_runtime.h>
#include <cmath>

// NCE LM loss. N = B*T rows, D = 1024, K = 20 noise ids, V = vocab.
// R7 = R5 minus the per-block tail: each wave's lane 0 writes its own term
// to cb4[row*4+wave] (no closing barrier/LDS in kernel1); finalize sums
// 4N floats as float4 with a fixed tree. No atomics, no memset.

#define KN 20            // noise count (fast path)

__device__ __forceinline__ float log_sigmoid_f(float x) {
    // stable log(sigmoid(x)) = min(x,0) - log1p(exp(-|x|))
    return fminf(x, 0.0f) - log1pf(expf(-fabsf(x)));
}

__device__ __forceinline__ float fma4(float4 a, float4 b, float acc) {
    acc = fmaf(a.x, b.x, acc);
    acc = fmaf(a.y, b.y, acc);
    acc = fmaf(a.z, b.z, acc);
    return fmaf(a.w, b.w, acc);
}

__device__ __forceinline__ float wave_reduce(float v) {
    #pragma unroll
    for (int off = 32; off > 0; off >>= 1) v += __shfl_xor(v, off, 64);
    return v;
}

// One row per block. Wave w owns ids {w, w+4, ...} <= 20 (id 0 = target row).
__global__ __launch_bounds__(256) void nce_rows_kernel(
    const float* __restrict__ hidden,     // (N, 1024)
    const int*   __restrict__ targets,    // (N,)
    const float* __restrict__ W,          // (V, 1024)
    const int*   __restrict__ noise_ids,  // (20,)
    float* __restrict__ cb4,              // (4N,) per-wave loss contributions
    float inv_n, float inv_nk, float shift)
{
    const int row  = blockIdx.x;
    const int tid  = threadIdx.x;
    const int wave = tid >> 6;
    const int lane = tid & 63;

    // Hidden row chunk in registers: lane owns elems {lane*4 + j*256}.
    const float* hrow = hidden + (size_t)row * 1024;
    float4 h[4];
    #pragma unroll
    for (int j = 0; j < 4; ++j)
        h[j] = *reinterpret_cast<const float4*>(hrow + lane * 4 + j * 256);

    const int tgt = targets[row];

    // Phase 1: lane-local partials for up to 6 dots (static accumulators).
    float acc[6];
    #pragma unroll
    for (int s = 0; s < 6; ++s) {
        const int id = wave + 4 * s;
        float a = 0.0f;
        if (id <= KN) {
            const int wrow = (id == 0) ? tgt : noise_ids[id - 1];
            const float* wr = W + (size_t)wrow * 1024;
            #pragma unroll
            for (int j = 0; j < 4; ++j) {
                const float4 b = *reinterpret_cast<const float4*>(wr + lane * 4 + j * 256);
                a = fma4(h[j], b, a);
            }
        }
        acc[s] = a;
    }

    // Phase 2: 6 butterflies, round-major so independent chains pipeline.
    // Afterwards every lane holds all 6 full sums.
    #pragma unroll
    for (int off = 32; off > 0; off >>= 1)
        #pragma unroll
        for (int s = 0; s < 6; ++s)
            acc[s] += __shfl_xor(acc[s], off, 64);

    // Phase 3: lanes 0..5 evaluate their log-sigmoid term in parallel,
    // sum across lanes 0..7, wave leader stores -- block exits, no barrier.
    float v = acc[0];
    v = (lane == 1) ? acc[1] : v;
    v = (lane == 2) ? acc[2] : v;
    v = (lane == 3) ? acc[3] : v;
    v = (lane == 4) ? acc[4] : v;
    v = (lane == 5) ? acc[5] : v;
    const int id = wave + 4 * lane;
    float term = 0.0f;
    if (lane < 6 && id <= KN) {
        const float sc = v + shift;
        term = (id == 0) ? (-log_sigmoid_f(sc)) * inv_n
                         : (-log_sigmoid_f(-sc)) * inv_nk;
    }
    term += __shfl_xor(term, 1, 64);
    term += __shfl_xor(term, 2, 64);
    term += __shfl_xor(term, 4, 64);

    if (lane == 0) cb4[row * 4 + wave] = term;
}

// ---- generic fallback for unexpected shapes: one block per row ----
__global__ __launch_bounds__(256) void nce_generic_kernel(
    const float* __restrict__ hidden, const int* __restrict__ targets,
    const float* __restrict__ W, const int* __restrict__ noise_ids,
    float* __restrict__ cb4, int D, int K, float inv_n, float inv_nk, float shift)
{
    const int row  = blockIdx.x;
    const int tid  = threadIdx.x;
    const int wave = tid >> 6;
    const int lane = tid & 63;

    const float* hrow = hidden + (size_t)row * D;
    const int tgt = targets[row];
    float c = 0.0f;
    for (int id = wave; id <= K; id += 4) {
        const int wrow = (id == 0) ? tgt : noise_ids[id - 1];
        const float* wv = W + (size_t)wrow * D;
        float acc = 0.0f;
        for (int k = lane; k < D; k += 64) acc = fmaf(hrow[k], wv[k], acc);
        acc = wave_reduce(acc);
        if (lane == 0) {
            const float s = acc + shift;
            c += (id == 0) ? (-log_sigmoid_f(s)) * inv_n
                           : (-log_sigmoid_f(-s)) * inv_nk;
        }
    }
    if (lane == 0) cb4[row * 4 + wave] = c;
}

// Deterministic fixed-tree sum of 4N per-wave contributions (read as float4).
__global__ __launch_bounds__(256) void nce_sum_kernel(
    const float* __restrict__ cb4, float* __restrict__ out, int n4)
{
    __shared__ float sp[4];
    const int tid  = threadIdx.x;
    const int wave = tid >> 6;
    const int lane = tid & 63;

    const float4* v = reinterpret_cast<const float4*>(cb4);
    const int nv = n4 >> 2;
    float p = 0.0f;
    for (int i = tid; i < nv; i += 256) {
        const float4 x = v[i];
        p += (x.x + x.y) + (x.z + x.w);
    }
    p = wave_reduce(p);
    if (lane == 0) sp[wave] = p;
    __syncthreads();
    if (tid == 0) out[0] = sp[0] + sp[1] + sp[2] + sp[3];
}

extern "C" void kernel_launch(void* const* d_in, const int* in_sizes, int n_in,
                              void* d_out, int out_size, void* d_ws, size_t ws_size,
                              hipStream_t stream) {
    const float* hidden    = (const float*)d_in[0];
    const int*   targets   = (const int*)d_in[1];
    const float* W         = (const float*)d_in[2];
    const int*   noise_ids = (const int*)d_in[3];

    const int N = in_sizes[1];             // B*T = 2048
    const int D = in_sizes[0] / N;         // 1024
    const int K = in_sizes[3];             // 20
    const int V = in_sizes[2] / D;         // 50257

    const float shift  = logf((float)V) - logf((float)K);
    const float inv_n  = 1.0f / (float)N;
    const float inv_nk = 1.0f / ((float)N * (float)K);

    float* cb4 = (float*)d_ws;             // 4N floats, all overwritten each call

    if (D == 1024 && K == KN) {
        nce_rows_kernel<<<N, 256, 0, stream>>>(
            hidden, targets, W, noise_ids, cb4, inv_n, inv_nk, shift);
    } else {
        nce_generic_kernel<<<N, 256, 0, stream>>>(
            hidden, targets, W, noise_ids, cb4, D, K, inv_n, inv_nk, shift);
    }
    nce_sum_kernel<<<1, 256, 0, stream>>>(cb4, (float*)d_out, 4 * N);
}

// Round 8
// 16.477 us; speedup vs baseline: 3.5976x; 1.0811x over previous
//
#include <hip/hip_runtime.h>
#include <cmath>

// NCE LM loss. N = B*T rows, D = 1024, K = 20 noise ids, V = vocab.
// R8: 2 rows/block at FULL occupancy: 1024 blocks x 512 thr (8 waves)
// = 8192 waves = 32 waves/CU. Both hidden rows staged in 8KB LDS (keeps
// VGPR low -> occupancy preserved); each W noise chunk read once serves
// both rows -> L2 read traffic ~180MB -> ~98MB. Per-wave terms written
// directly (no closing barrier); finalize = fixed-tree float4 sum.

#define KN 20            // noise count (fast path)

__device__ __forceinline__ float log_sigmoid_f(float x) {
    // stable log(sigmoid(x)) = min(x,0) - log1p(exp(-|x|))
    return fminf(x, 0.0f) - log1pf(expf(-fabsf(x)));
}

__device__ __forceinline__ float fma4(float4 a, float4 b, float acc) {
    acc = fmaf(a.x, b.x, acc);
    acc = fmaf(a.y, b.y, acc);
    acc = fmaf(a.z, b.z, acc);
    return fmaf(a.w, b.w, acc);
}

__device__ __forceinline__ float wave_reduce(float v) {
    #pragma unroll
    for (int off = 32; off > 0; off >>= 1) v += __shfl_xor(v, off, 64);
    return v;
}

// 2 rows per block, 8 waves. Noise id ownership: slot0 = wave, slot1 = wave+8,
// slot2 = (wave<4 ? noise 16+wave : wave<6 ? target row wave-4 : none).
__global__ __launch_bounds__(512) void nce_rows2_kernel(
    const float* __restrict__ hidden,     // (N, 1024)
    const int*   __restrict__ targets,    // (N,)
    const float* __restrict__ W,          // (V, 1024)
    const int*   __restrict__ noise_ids,  // (20,)
    float* __restrict__ cbw,              // (8*nblocks,) per-wave contributions
    float inv_n, float inv_nk, float shift)
{
    __shared__ float hlds[2048];          // 8 KB: two hidden rows

    const int tid  = threadIdx.x;
    const int wave = tid >> 6;            // 0..7
    const int lane = tid & 63;
    const int r0   = blockIdx.x * 2;

    // Stage both hidden rows: thread t loads float4 #t of 512 (one 8KB
    // coalesced read), linear LDS write.
    reinterpret_cast<float4*>(hlds)[tid] =
        reinterpret_cast<const float4*>(hidden + (size_t)r0 * 1024)[tid];

    const int tgt0 = targets[r0];
    const int tgt1 = targets[r0 + 1];
    __syncthreads();

    float acc[3][2];
    #pragma unroll
    for (int s = 0; s < 3; ++s) { acc[s][0] = 0.0f; acc[s][1] = 0.0f; }

    // Slots 0,1: noise ids wave, wave+8 — one W chunk serves both rows.
    #pragma unroll
    for (int s = 0; s < 2; ++s) {
        const int n = wave + 8 * s;
        const float* wr = W + (size_t)noise_ids[n] * 1024;
        #pragma unroll
        for (int j = 0; j < 4; ++j) {
            const float4 b  = *reinterpret_cast<const float4*>(wr + lane * 4 + j * 256);
            const float4 a0 = *reinterpret_cast<const float4*>(hlds + lane * 4 + j * 256);
            const float4 a1 = *reinterpret_cast<const float4*>(hlds + 1024 + lane * 4 + j * 256);
            acc[s][0] = fma4(b, a0, acc[s][0]);
            acc[s][1] = fma4(b, a1, acc[s][1]);
        }
    }

    // Slot 2: waves 0..3 -> noise ids 16..19 (both rows);
    //         waves 4,5 -> target dot for row wave-4; waves 6,7 idle.
    if (wave < 4) {
        const float* wr = W + (size_t)noise_ids[16 + wave] * 1024;
        #pragma unroll
        for (int j = 0; j < 4; ++j) {
            const float4 b  = *reinterpret_cast<const float4*>(wr + lane * 4 + j * 256);
            const float4 a0 = *reinterpret_cast<const float4*>(hlds + lane * 4 + j * 256);
            const float4 a1 = *reinterpret_cast<const float4*>(hlds + 1024 + lane * 4 + j * 256);
            acc[2][0] = fma4(b, a0, acc[2][0]);
            acc[2][1] = fma4(b, a1, acc[2][1]);
        }
    } else if (wave < 6) {
        const int r = wave - 4;
        const float* wr = W + (size_t)(r == 0 ? tgt0 : tgt1) * 1024;
        const float* hr = hlds + r * 1024;
        #pragma unroll
        for (int j = 0; j < 4; ++j) {
            const float4 b = *reinterpret_cast<const float4*>(wr + lane * 4 + j * 256);
            const float4 a = *reinterpret_cast<const float4*>(hr + lane * 4 + j * 256);
            acc[2][0] = fma4(b, a, acc[2][0]);
        }
    }

    // 6 butterflies, round-major so independent chains pipeline.
    #pragma unroll
    for (int off = 32; off > 0; off >>= 1)
        #pragma unroll
        for (int s = 0; s < 3; ++s) {
            acc[s][0] += __shfl_xor(acc[s][0], off, 64);
            acc[s][1] += __shfl_xor(acc[s][1], off, 64);
        }

    // Lanes 0..5 evaluate terms in parallel: lane -> (slot=lane>>1, row=lane&1).
    float v = acc[0][0];
    v = (lane == 1) ? acc[0][1] : v;
    v = (lane == 2) ? acc[1][0] : v;
    v = (lane == 3) ? acc[1][1] : v;
    v = (lane == 4) ? acc[2][0] : v;
    v = (lane == 5) ? acc[2][1] : v;

    float term = 0.0f;
    if (lane < 6) {
        const bool valid  = (lane < 4) || (wave < 4) || (lane == 4 && wave < 6);
        const bool is_pos = (lane == 4 && wave >= 4);   // target dots
        if (valid) {
            const float sc = v + shift;
            term = is_pos ? (-log_sigmoid_f(sc)) * inv_n
                          : (-log_sigmoid_f(-sc)) * inv_nk;
        }
    }
    term += __shfl_xor(term, 1, 64);
    term += __shfl_xor(term, 2, 64);
    term += __shfl_xor(term, 4, 64);

    if (lane == 0) cbw[blockIdx.x * 8 + wave] = term;
}

// ---- generic fallback for unexpected shapes: one block per row ----
__global__ __launch_bounds__(256) void nce_generic_kernel(
    const float* __restrict__ hidden, const int* __restrict__ targets,
    const float* __restrict__ W, const int* __restrict__ noise_ids,
    float* __restrict__ cb4, int D, int K, float inv_n, float inv_nk, float shift)
{
    const int row  = blockIdx.x;
    const int tid  = threadIdx.x;
    const int wave = tid >> 6;
    const int lane = tid & 63;

    const float* hrow = hidden + (size_t)row * D;
    const int tgt = targets[row];
    float c = 0.0f;
    for (int id = wave; id <= K; id += 4) {
        const int wrow = (id == 0) ? tgt : noise_ids[id - 1];
        const float* wv = W + (size_t)wrow * D;
        float acc = 0.0f;
        for (int k = lane; k < D; k += 64) acc = fmaf(hrow[k], wv[k], acc);
        acc = wave_reduce(acc);
        if (lane == 0) {
            const float s = acc + shift;
            c += (id == 0) ? (-log_sigmoid_f(s)) * inv_n
                           : (-log_sigmoid_f(-s)) * inv_nk;
        }
    }
    if (lane == 0) cb4[row * 4 + wave] = c;
}

// Deterministic fixed-tree sum of n4 per-wave contributions (read as float4).
__global__ __launch_bounds__(256) void nce_sum_kernel(
    const float* __restrict__ cbw, float* __restrict__ out, int n4)
{
    __shared__ float sp[4];
    const int tid  = threadIdx.x;
    const int wave = tid >> 6;
    const int lane = tid & 63;

    const float4* v = reinterpret_cast<const float4*>(cbw);
    const int nv = n4 >> 2;
    float p = 0.0f;
    for (int i = tid; i < nv; i += 256) {
        const float4 x = v[i];
        p += (x.x + x.y) + (x.z + x.w);
    }
    p = wave_reduce(p);
    if (lane == 0) sp[wave] = p;
    __syncthreads();
    if (tid == 0) out[0] = sp[0] + sp[1] + sp[2] + sp[3];
}

extern "C" void kernel_launch(void* const* d_in, const int* in_sizes, int n_in,
                              void* d_out, int out_size, void* d_ws, size_t ws_size,
                              hipStream_t stream) {
    const float* hidden    = (const float*)d_in[0];
    const int*   targets   = (const int*)d_in[1];
    const float* W         = (const float*)d_in[2];
    const int*   noise_ids = (const int*)d_in[3];

    const int N = in_sizes[1];             // B*T = 2048
    const int D = in_sizes[0] / N;         // 1024
    const int K = in_sizes[3];             // 20
    const int V = in_sizes[2] / D;         // 50257

    const float shift  = logf((float)V) - logf((float)K);
    const float inv_n  = 1.0f / (float)N;
    const float inv_nk = 1.0f / ((float)N * (float)K);

    float* cbw = (float*)d_ws;             // 4N floats, all overwritten each call

    if (D == 1024 && K == KN && (N % 2) == 0) {
        nce_rows2_kernel<<<N / 2, 512, 0, stream>>>(
            hidden, targets, W, noise_ids, cbw, inv_n, inv_nk, shift);
    } else {
        nce_generic_kernel<<<N, 256, 0, stream>>>(
            hidden, targets, W, noise_ids, cbw, D, K, inv_n, inv_nk, shift);
    }
    nce_sum_kernel<<<1, 256, 0, stream>>>(cbw, (float*)d_out, 4 * N);
}